// Round 2
// baseline (149.727 us; speedup 1.0000x reference)
//
#include <hip/hip_runtime.h>
#include <hip/hip_bf16.h>

// Problem constants (B=16, N=8192, C=128, H=2, hd=64) — fp32 I/O
#define B_      16
#define N_      8192
#define C_      128
#define HD_     64
#define TILE_N  128
#define NBLK    (N_ / TILE_N)        // 64 blocks per batch
#define PART_STRIDE 260              // m0,m1,l0,l1, xa0[128], xa1[128]

// ---------------------------------------------------------------------------
// Kernel 1: per-(b, n-tile) — logits s[h][n] = x·q_eff[h], block-local
// softmax partials (m, l), and weighted sums xa[h][c] = sum_n exp(s-m)*x[n][c].
// Writes a 260-float partial record per block.
// ---------------------------------------------------------------------------
__global__ __launch_bounds__(TILE_N) void k_partial(
    const float* __restrict__ x,
    const float* __restrict__ Wk,
    const float* __restrict__ mem,
    float* __restrict__ part)
{
    __shared__ float qeff[2][C_];
    __shared__ float sl[2][TILE_N];    // softmax weights per row
    __shared__ float red[2][TILE_N];   // reduction scratch

    const int t   = threadIdx.x;
    const int blk = blockIdx.x;
    const int b   = blk / NBLK;
    const int n0  = (blk % NBLK) * TILE_N;

    // q_eff[h][c] = scale * sum_j mem[h, 2j+g] * Wk[g, h*32+j, i]
    // (c = g*64 + i; folds interleaved grouped-linear channel map + mem dot)
    {
        const int c = t, g = c >> 6, i = c & 63;
        float a0 = 0.f, a1 = 0.f;
        for (int j = 0; j < 32; ++j) {
            a0 += mem[2 * j + g]      * Wk[g * 4096 + j        * 64 + i];
            a1 += mem[64 + 2 * j + g] * Wk[g * 4096 + (32 + j) * 64 + i];
        }
        qeff[0][c] = 0.125f * a0;   // scale = hd^-0.5 = 0.125
        qeff[1][c] = 0.125f * a1;
    }
    __syncthreads();

    // phase 1: one row per thread, logits via float4 loads
    const int n = n0 + t;
    const float4* xr = (const float4*)(x + ((size_t)b * N_ + n) * C_);
    float s0 = 0.f, s1 = 0.f;
    #pragma unroll
    for (int v = 0; v < 32; ++v) {
        const float4 q = xr[v];
        const int c0 = v * 4;
        s0 += q.x * qeff[0][c0]     + q.y * qeff[0][c0 + 1]
            + q.z * qeff[0][c0 + 2] + q.w * qeff[0][c0 + 3];
        s1 += q.x * qeff[1][c0]     + q.y * qeff[1][c0 + 1]
            + q.z * qeff[1][c0 + 2] + q.w * qeff[1][c0 + 3];
    }

    // block max
    red[0][t] = s0; red[1][t] = s1;
    __syncthreads();
    for (int off = TILE_N / 2; off > 0; off >>= 1) {
        if (t < off) {
            red[0][t] = fmaxf(red[0][t], red[0][t + off]);
            red[1][t] = fmaxf(red[1][t], red[1][t + off]);
        }
        __syncthreads();
    }
    const float m0 = red[0][0], m1 = red[1][0];
    __syncthreads();

    // weights + block sum
    const float w0 = __expf(s0 - m0), w1 = __expf(s1 - m1);
    sl[0][t] = w0; sl[1][t] = w1;
    red[0][t] = w0; red[1][t] = w1;
    __syncthreads();
    for (int off = TILE_N / 2; off > 0; off >>= 1) {
        if (t < off) {
            red[0][t] += red[0][t + off];
            red[1][t] += red[1][t + off];
        }
        __syncthreads();
    }
    const float l0 = red[0][0], l1 = red[1][0];

    // phase 2: channel-parallel weighted sum (re-read tile; L1/L2-hot,
    // perfectly coalesced: lane c reads column c)
    const int c = t;
    const float* xcol = x + ((size_t)b * N_ + n0) * C_ + c;
    float a0 = 0.f, a1 = 0.f;
    for (int r = 0; r < TILE_N; ++r) {
        const float xf = xcol[(size_t)r * C_];
        a0 += sl[0][r] * xf;
        a1 += sl[1][r] * xf;
    }

    float* p = part + (size_t)blk * PART_STRIDE;
    p[4 + c]       = a0;
    p[4 + 128 + c] = a1;
    if (t == 0) { p[0] = m0; p[1] = m1; p[2] = l0; p[3] = l1; }
}

// ---------------------------------------------------------------------------
// Kernel 2: combine partials per batch -> xa -> row (Wv) -> F (Wp, bp).
// F[b*2+h][cc] (cc = o*2+g), 32 slabs x 128 floats.
// Note: the broadcast+reshape means the 128-ch input to Wp is row[h][0:64]
// duplicated twice (channel c' maps to d = c'&63), handled in the Wv stage
// by only ever using rowv[h][d], then F = bp[g,o] + sum_i rowv[h,i]*Wp[g,o,i].
// ---------------------------------------------------------------------------
__global__ __launch_bounds__(256) void k_combine(
    const float* __restrict__ part,
    const float* __restrict__ Wv,
    const float* __restrict__ Wp,
    const float* __restrict__ bp,
    float* __restrict__ Fbuf)
{
    __shared__ float ml[4][NBLK];
    __shared__ float xan[2][C_];
    __shared__ float rowv[2][HD_];

    const int t = threadIdx.x;
    const int b = blockIdx.x;

    if (t < NBLK) {
        const float* p = part + ((size_t)b * NBLK + t) * PART_STRIDE;
        ml[0][t] = p[0]; ml[1][t] = p[1]; ml[2][t] = p[2]; ml[3][t] = p[3];
    }
    __syncthreads();

    const int h = t >> 7, c = t & 127;
    float M = -1e30f;
    for (int k = 0; k < NBLK; ++k) M = fmaxf(M, ml[h][k]);
    float L = 0.f;
    for (int k = 0; k < NBLK; ++k) L += ml[2 + h][k] * __expf(ml[h][k] - M);
    float xa = 0.f;
    for (int k = 0; k < NBLK; ++k) {
        const float* p = part + ((size_t)b * NBLK + k) * PART_STRIDE;
        xa += p[4 + h * C_ + c] * __expf(ml[h][k] - M);
    }
    xan[h][c] = xa / L;
    __syncthreads();

    // row[h,d] = sum_i xan[h, g*64+i] * Wv[g, h*32+(d>>1), i],  g = d&1
    if (t < 128) {
        const int hh = t >> 6, d = t & 63, g = d & 1, o = hh * 32 + (d >> 1);
        const float* wv = Wv + g * 4096 + o * 64;
        const float* xv = &xan[hh][g * 64];
        float acc = 0.f;
        for (int i = 0; i < 64; ++i) acc += xv[i] * wv[i];
        rowv[hh][d] = acc;
    }
    __syncthreads();

    // F[h, o*2+g] = bp[g,o] + sum_i rowv[h,i] * Wp[g,o,i]
    {
        const int hh = t >> 7, cc = t & 127, g = cc & 1, o = cc >> 1;
        const float* wp = Wp + g * 4096 + o * 64;
        float acc = bp[g * 64 + o];
        for (int i = 0; i < 64; ++i) acc += rowv[hh][i] * wp[i];
        Fbuf[(b * 2 + hh) * C_ + cc] = acc;
    }
}

// ---------------------------------------------------------------------------
// Kernel 3: broadcast F to the output: out[b,n,:] = F[b*2 + (n>=4096)][:].
// Whole F table (32 slabs x 128 fp32 = 16 KB) cached in LDS; pure streaming
// float4 stores, exact coverage of 4,194,304 float4.
// ---------------------------------------------------------------------------
__global__ __launch_bounds__(256) void k_bcast(
    const float4* __restrict__ F4,
    float4* __restrict__ out4)
{
    __shared__ float4 Ftab[1024];            // 32 slabs * 32 float4
    const int t = threadIdx.x;
    for (int i = t; i < 1024; i += 256) Ftab[i] = F4[i];
    __syncthreads();

    size_t idx = (size_t)blockIdx.x * 256 + t;
    const size_t stride = (size_t)2048 * 256;
    #pragma unroll
    for (int k = 0; k < 8; ++k) {
        // slab = idx>>17 (row of 32 float4 per 128-float out row, 4096 rows/slab)
        out4[idx] = Ftab[((idx >> 17) << 5) | (idx & 31)];
        idx += stride;
    }
}

extern "C" void kernel_launch(void* const* d_in, const int* in_sizes, int n_in,
                              void* d_out, int out_size, void* d_ws, size_t ws_size,
                              hipStream_t stream)
{
    const float* x   = (const float*)d_in[0];
    const float* Wk  = (const float*)d_in[1];
    const float* Wv  = (const float*)d_in[2];
    const float* Wp  = (const float*)d_in[3];
    const float* bp  = (const float*)d_in[4];
    const float* mem = (const float*)d_in[5];

    float* part = (float*)d_ws;
    // partials: 1024 blocks * 260 floats = 1,064,960 B (16B-aligned)
    float* Fbuf = (float*)((char*)d_ws + (size_t)B_ * NBLK * PART_STRIDE * sizeof(float));

    k_partial<<<dim3(B_ * NBLK), dim3(TILE_N), 0, stream>>>(x, Wk, mem, part);
    k_combine<<<dim3(B_), dim3(256), 0, stream>>>(part, Wv, Wp, bp, Fbuf);
    k_bcast<<<dim3(2048), dim3(256), 0, stream>>>((const float4*)Fbuf,
                                                  (float4*)d_out);
}

// Round 4
// 144.082 us; speedup vs baseline: 1.0392x; 1.0392x over previous
//
#include <hip/hip_runtime.h>
#include <hip/hip_bf16.h>

// Problem constants (B=16, N=8192, C=128, H=2, hd=64) — fp32 I/O
#define B_      16
#define N_      8192
#define C_      128
#define HD_     64
#define TILE_N  128
#define NBLK    (N_ / TILE_N)        // 64 tiles per batch
#define PART_STRIDE 260              // m0,m1,l0,l1, xa0[128], xa1[128]

typedef float v4f __attribute__((ext_vector_type(4)));   // native vec for nontemporal

// ---------------------------------------------------------------------------
// Kernel 1: per-(b, n-tile) — logits s[h][n] = x·q_eff[h], block-local
// softmax partials (m, l), weighted sums xa[h][c] = sum_n exp(s-m)*x[n][c].
// 256 threads/block (4 waves): 2 threads per row in phase 1, 2 threads per
// channel in phase 2. Shuffle reductions; one 260-float record per block.
// ---------------------------------------------------------------------------
__global__ __launch_bounds__(256) void k_partial(
    const float* __restrict__ x,
    const float* __restrict__ Wk,
    const float* __restrict__ mem,
    float* __restrict__ part)
{
    __shared__ float qeff0[C_], qeff1[C_];
    __shared__ float sp0[2][TILE_N], sp1[2][TILE_N];   // per-half logit partials
    __shared__ float sl0[TILE_N], sl1[TILE_N];         // softmax weights
    __shared__ float pa0[2][C_], pa1[2][C_];           // per-half xa partials
    __shared__ float redm[8];

    const int t   = threadIdx.x;
    const int blk = blockIdx.x;
    const int b   = blk / NBLK;
    const int n0  = (blk % NBLK) * TILE_N;

    // q_eff[h][c] = 0.125 * sum_j mem[h, 2j+g] * Wk[g, h*32+j, i]
    // (c = g*64+i); 256 threads -> one (h,c) each.
    {
        const int h = t >> 7, c = t & 127, g = c >> 6, i = c & 63;
        const float* wkb = Wk + g * 4096 + (h * 32) * 64 + i;
        const float* mr  = mem + h * 64 + g;
        float a = 0.f;
        #pragma unroll
        for (int j = 0; j < 32; ++j) a += mr[2 * j] * wkb[j * 64];
        if (h == 0) qeff0[c] = 0.125f * a; else qeff1[c] = 0.125f * a;
    }
    __syncthreads();

    // phase 1: 2 threads per row, 16 float4 each (64 channels)
    const int r = t & 127, half = t >> 7;
    {
        const float4* xr = (const float4*)(x + ((size_t)b * N_ + n0 + r) * C_ + half * 64);
        float p0 = 0.f, p1 = 0.f;
        #pragma unroll
        for (int v = 0; v < 16; ++v) {
            const float4 q = xr[v];
            const int c0 = half * 64 + v * 4;
            p0 += q.x * qeff0[c0]     + q.y * qeff0[c0 + 1]
                + q.z * qeff0[c0 + 2] + q.w * qeff0[c0 + 3];
            p1 += q.x * qeff1[c0]     + q.y * qeff1[c0 + 1]
                + q.z * qeff1[c0 + 2] + q.w * qeff1[c0 + 3];
        }
        sp0[half][r] = p0;
        sp1[half][r] = p1;
    }
    __syncthreads();

    // rows 0..127 live on threads 0..127 (waves 0,1)
    float s0 = 0.f, s1 = 0.f;
    if (t < TILE_N) {
        s0 = sp0[0][t] + sp0[1][t];
        s1 = sp1[0][t] + sp1[1][t];
    }
    // wave max (width 64) then cross-wave via LDS
    float m0 = s0, m1 = s1;
    #pragma unroll
    for (int off = 32; off > 0; off >>= 1) {
        m0 = fmaxf(m0, __shfl_xor(m0, off));
        m1 = fmaxf(m1, __shfl_xor(m1, off));
    }
    if (t == 0)  { redm[0] = m0; redm[1] = m1; }
    if (t == 64) { redm[2] = m0; redm[3] = m1; }
    __syncthreads();
    m0 = fmaxf(redm[0], redm[2]);
    m1 = fmaxf(redm[1], redm[3]);

    // weights + block sum
    float w0 = 0.f, w1 = 0.f;
    if (t < TILE_N) {
        w0 = __expf(s0 - m0);
        w1 = __expf(s1 - m1);
        sl0[t] = w0;
        sl1[t] = w1;
    }
    float l0 = w0, l1 = w1;
    #pragma unroll
    for (int off = 32; off > 0; off >>= 1) {
        l0 += __shfl_xor(l0, off);
        l1 += __shfl_xor(l1, off);
    }
    if (t == 0)  { redm[4] = l0; redm[5] = l1; }
    if (t == 64) { redm[6] = l0; redm[7] = l1; }
    __syncthreads();

    // phase 2: 2 threads per channel, 64 rows each (tile is L1/L2-hot)
    {
        const int c = t & 127, rh = t >> 7;
        const float* xcol = x + ((size_t)b * N_ + n0 + rh * 64) * C_ + c;
        const float* wr0 = &sl0[rh * 64];
        const float* wr1 = &sl1[rh * 64];
        float a0 = 0.f, a1 = 0.f;
        #pragma unroll 8
        for (int k = 0; k < 64; ++k) {
            const float xf = xcol[(size_t)k * C_];
            a0 += wr0[k] * xf;
            a1 += wr1[k] * xf;
        }
        pa0[rh][c] = a0;
        pa1[rh][c] = a1;
    }
    __syncthreads();

    float* p = part + (size_t)blk * PART_STRIDE;
    if (t < C_) {
        p[4 + t]       = pa0[0][t] + pa0[1][t];
        p[4 + C_ + t]  = pa1[0][t] + pa1[1][t];
    }
    if (t == 0) {
        p[0] = m0; p[1] = m1;
        p[2] = redm[4] + redm[6];
        p[3] = redm[5] + redm[7];
    }
}

// ---------------------------------------------------------------------------
// Kernel 2: combine partials per batch -> xa -> row (Wv) -> F (Wp, bp).
// F[b*2+h][cc] (cc = o*2+g), 32 slabs x 128 floats.
// ---------------------------------------------------------------------------
__global__ __launch_bounds__(256) void k_combine(
    const float* __restrict__ part,
    const float* __restrict__ Wv,
    const float* __restrict__ Wp,
    const float* __restrict__ bp,
    float* __restrict__ Fbuf)
{
    __shared__ float ml[4][NBLK];
    __shared__ float xan[2][C_];
    __shared__ float rowv[2][HD_];

    const int t = threadIdx.x;
    const int b = blockIdx.x;

    if (t < NBLK) {
        const float* p = part + ((size_t)b * NBLK + t) * PART_STRIDE;
        ml[0][t] = p[0]; ml[1][t] = p[1]; ml[2][t] = p[2]; ml[3][t] = p[3];
    }
    __syncthreads();

    const int h = t >> 7, c = t & 127;
    float M = -1e30f;
    for (int k = 0; k < NBLK; ++k) M = fmaxf(M, ml[h][k]);
    float L = 0.f;
    for (int k = 0; k < NBLK; ++k) L += ml[2 + h][k] * __expf(ml[h][k] - M);
    float xa = 0.f;
    for (int k = 0; k < NBLK; ++k) {
        const float* p = part + ((size_t)b * NBLK + k) * PART_STRIDE;
        xa += p[4 + h * C_ + c] * __expf(ml[h][k] - M);
    }
    xan[h][c] = xa / L;
    __syncthreads();

    // row[h,d] = sum_i xan[h, g*64+i] * Wv[g, h*32+(d>>1), i],  g = d&1
    if (t < 128) {
        const int hh = t >> 6, d = t & 63, g = d & 1, o = hh * 32 + (d >> 1);
        const float* wv = Wv + g * 4096 + o * 64;
        const float* xv = &xan[hh][g * 64];
        float acc = 0.f;
        for (int i = 0; i < 64; ++i) acc += xv[i] * wv[i];
        rowv[hh][d] = acc;
    }
    __syncthreads();

    // F[h, o*2+g] = bp[g,o] + sum_i rowv[h,i] * Wp[g,o,i]
    {
        const int hh = t >> 7, cc = t & 127, g = cc & 1, o = cc >> 1;
        const float* wp = Wp + g * 4096 + o * 64;
        float acc = bp[g * 64 + o];
        for (int i = 0; i < 64; ++i) acc += rowv[hh][i] * wp[i];
        Fbuf[(b * 2 + hh) * C_ + cc] = acc;
    }
}

// ---------------------------------------------------------------------------
// Kernel 3: broadcast F to the output: out[b,n,:] = F[b*2 + (n>=4096)][:].
// F table (16 KB) in LDS; nontemporal native-vec float4 streaming stores.
// ---------------------------------------------------------------------------
__global__ __launch_bounds__(256) void k_bcast(
    const v4f* __restrict__ F4,
    v4f* __restrict__ out4)
{
    __shared__ v4f Ftab[1024];               // 32 slabs * 32 float4
    const int t = threadIdx.x;
    for (int i = t; i < 1024; i += 256) Ftab[i] = F4[i];
    __syncthreads();

    size_t idx = (size_t)blockIdx.x * 256 + t;
    const size_t stride = (size_t)2048 * 256;
    #pragma unroll
    for (int k = 0; k < 8; ++k) {
        // slab = idx>>17; each out row = 32 float4
        const v4f v = Ftab[((idx >> 17) << 5) | (idx & 31)];
        __builtin_nontemporal_store(v, &out4[idx]);
        idx += stride;
    }
}

extern "C" void kernel_launch(void* const* d_in, const int* in_sizes, int n_in,
                              void* d_out, int out_size, void* d_ws, size_t ws_size,
                              hipStream_t stream)
{
    const float* x   = (const float*)d_in[0];
    const float* Wk  = (const float*)d_in[1];
    const float* Wv  = (const float*)d_in[2];
    const float* Wp  = (const float*)d_in[3];
    const float* bp  = (const float*)d_in[4];
    const float* mem = (const float*)d_in[5];

    float* part = (float*)d_ws;
    // partials: 1024 blocks * 260 floats = 1,064,960 B
    float* Fbuf = (float*)((char*)d_ws + (size_t)B_ * NBLK * PART_STRIDE * sizeof(float));

    k_partial<<<dim3(B_ * NBLK), dim3(256), 0, stream>>>(x, Wk, mem, part);
    k_combine<<<dim3(B_), dim3(256), 0, stream>>>(part, Wv, Wp, bp, Fbuf);
    k_bcast<<<dim3(2048), dim3(256), 0, stream>>>((const v4f*)Fbuf,
                                                  (v4f*)d_out);
}